// Round 19
// baseline (2020.476 us; speedup 1.0000x reference)
//
#include <hip/hip_runtime.h>
#include <cstdint>
#include <cstddef>

#define T_STEPS 1024
#define NB 64
#define DIN 256
#define DH 256
#define DW 512            // DIN + DH (row width of each W)
#define G4 1024           // 4*DH gate rows

typedef _Float16 h2 __attribute__((ext_vector_type(2)));
typedef _Float16 h4 __attribute__((ext_vector_type(4)));
typedef _Float16 h8 __attribute__((ext_vector_type(8)));
typedef float f4 __attribute__((ext_vector_type(4)));
typedef float f32x4 __attribute__((ext_vector_type(4)));
typedef int i4v __attribute__((ext_vector_type(4)));

static __device__ __forceinline__ float rcp_(float x) {
#if __has_builtin(__builtin_amdgcn_rcpf)
  return __builtin_amdgcn_rcpf(x);
#else
  return 1.0f / x;
#endif
}

static __device__ __forceinline__ float sigmoid_(float x) {
  return rcp_(1.f + __expf(-x));
}
static __device__ __forceinline__ float tanh_(float x) {
  float e = __expf(2.f * x);
  return 1.f - 2.f * rcp_(e + 1.f);
}

static __device__ __forceinline__ int sdot4_(int a, int b, int c) {
#if __has_builtin(__builtin_amdgcn_sdot4)
  return __builtin_amdgcn_sdot4(a, b, c, false);
#else
  int r = c;
#pragma unroll
  for (int k = 0; k < 4; ++k)
    r += (int)(signed char)(a >> (8 * k)) * (int)(signed char)(b >> (8 * k));
  return r;
#endif
}

// Pairwise lane swap (0<->1, ...) via DPP quad_perm [1,0,3,2] — pure VALU.
static __device__ __forceinline__ float dpp_swap1(float x) {
  int r = __builtin_amdgcn_update_dpp(0, __builtin_bit_cast(int, x),
                                      0xB1, 0xF, 0xF, true);
  return __builtin_bit_cast(float, r);
}

// ---------------------------------------------------------------------------
// x-part staging conversion (r15-exact): wxfs MFMA-staging order.
// ---------------------------------------------------------------------------
__global__ void kconv_w(const float* __restrict__ Wf, const float* __restrict__ Wi,
                        const float* __restrict__ Wg, const float* __restrict__ Wo,
                        h2* __restrict__ wxfs) {
  int kp = blockIdx.x >> 2;
  int gate = blockIdx.x & 3;
  int j = threadIdx.x;
  const float* W = gate == 0 ? Wf : gate == 1 ? Wi : gate == 2 ? Wg : Wo;
  const float* row = W + (size_t)j * DW;
  h2 v; v[0] = (_Float16)row[2*kp]; v[1] = (_Float16)row[2*kp + 1];
  int ks = kp >> 4, lg = (kp >> 2) & 3, slot = kp & 3;
  int nt = j >> 4, li = j & 15;
  size_t h8idx = (((size_t)gate * 8 + ks) * 16 + nt) * 64 + lg * 16 + li;
  wxfs[h8idx * 4 + slot] = v;
}

// ---------------------------------------------------------------------------
// h-part int8 quantization (r17-exact): per-row scale; cs = s/127.
// ---------------------------------------------------------------------------
__global__ void kscale(const float* __restrict__ Wf, const float* __restrict__ Wi,
                       const float* __restrict__ Wg, const float* __restrict__ Wo,
                       signed char* __restrict__ wq, float* __restrict__ cs) {
  int gate = blockIdx.x;
  int j = threadIdx.x;
  const float* W = gate == 0 ? Wf : gate == 1 ? Wi : gate == 2 ? Wg : Wo;
  const float* row = W + (size_t)j * DW + DIN;
  float amax = 1e-8f;
#pragma unroll 4
  for (int k4 = 0; k4 < 64; ++k4) {
    f4 v = *(const f4*)(row + 4 * k4);
    amax = fmaxf(amax, fmaxf(fmaxf(fabsf(v[0]), fabsf(v[1])),
                             fmaxf(fabsf(v[2]), fabsf(v[3]))));
  }
  int gr = gate * 256 + j;
  cs[gr] = amax / (127.f * 127.f);
  float inv = 127.f / amax;
  signed char* dst = wq + (size_t)gr * 256;
#pragma unroll 4
  for (int k4 = 0; k4 < 64; ++k4) {
    f4 v = *(const f4*)(row + 4 * k4);
#pragma unroll
    for (int u = 0; u < 4; ++u)
      dst[4 * k4 + u] = (signed char)__float2int_rn(v[u] * inv);
  }
}

// ---------------------------------------------------------------------------
// Phase 1 (MFMA v3, r15-exact — ~62us measured): Xg = x.Wx^T + bias.
// ---------------------------------------------------------------------------
__launch_bounds__(256, 2)
__global__ void kxgemm(const float* __restrict__ x,
                       const h8* __restrict__ wxfs,
                       const float* __restrict__ bf, const float* __restrict__ bi,
                       const float* __restrict__ bg, const float* __restrict__ bo,
                       _Float16* __restrict__ Xg,
                       int t0) {
  __shared__ char pool[65536];
  h8 (*xsf)[8][64] = (h8(*)[8][64])pool;               // 32KB A-frags
  h8 (*bs)[1024] = (h8(*)[1024])(pool + 32768);        // 2x16KB B slabs

  int tid = threadIdx.x;
  int l = tid & 63;
  int w = tid >> 6;
  int li = l & 15, lg = l >> 4;
  int tl = blockIdx.x >> 2;
  int nb = blockIdx.x & 3;
  int m0 = w * 16;

#pragma unroll
  for (int i = 0; i < 8; ++i) {
    int hi = tid + 256 * i;
    int sw  = hi >> 9;
    int sks = (hi >> 6) & 7;
    int sl  = hi & 63;
    int sli = sl & 15, slg = sl >> 4;
    const float* src = x + ((size_t)(t0 + tl) * NB + sw * 16 + sli) * DIN
                     + sks * 32 + slg * 8;
    f4 a0 = *(const f4*)src;
    f4 a1 = *(const f4*)(src + 4);
    h8 a;
    a[0] = (_Float16)a0[0]; a[1] = (_Float16)a0[1];
    a[2] = (_Float16)a0[2]; a[3] = (_Float16)a0[3];
    a[4] = (_Float16)a1[0]; a[5] = (_Float16)a1[1];
    a[6] = (_Float16)a1[2]; a[7] = (_Float16)a1[3];
    xsf[sw][sks][sl] = a;
  }
  {
    const h8* wsrc = wxfs + (size_t)(nb * 8 + 0) * 1024;
#pragma unroll
    for (int i = 0; i < 4; ++i) bs[0][tid + 256 * i] = wsrc[tid + 256 * i];
  }
  __syncthreads();

  f32x4 acc[16];
#pragma unroll
  for (int nt = 0; nt < 16; ++nt) {
    acc[nt][0] = 0.f; acc[nt][1] = 0.f; acc[nt][2] = 0.f; acc[nt][3] = 0.f;
  }

  for (int ks = 0; ks < 8; ++ks) {
    int buf = ks & 1;
    h8 ld0, ld1, ld2, ld3;
    if (ks < 7) {
      const h8* wn = wxfs + (size_t)(nb * 8 + ks + 1) * 1024;
      ld0 = wn[tid]; ld1 = wn[tid + 256]; ld2 = wn[tid + 512]; ld3 = wn[tid + 768];
    }
    h8 a = xsf[w][ks][l];
#pragma unroll
    for (int nt = 0; nt < 16; ++nt) {
      h8 bb = bs[buf][nt * 64 + l];
      acc[nt] = __builtin_amdgcn_mfma_f32_16x16x32_f16(a, bb, acc[nt], 0, 0, 0);
    }
    if (ks < 7) {
      h8* bt = bs[buf ^ 1];
      bt[tid] = ld0; bt[tid + 256] = ld1; bt[tid + 512] = ld2; bt[tid + 768] = ld3;
    }
    __syncthreads();
  }

  _Float16* osw = (_Float16*)(pool + (size_t)w * 8448);   // [16][264]
  const float* biasp = nb == 0 ? bf : nb == 1 ? bi : nb == 2 ? bg : bo;
#pragma unroll
  for (int nt = 0; nt < 16; ++nt) {
    float bv = biasp[nt * 16 + li];
#pragma unroll
    for (int r = 0; r < 4; ++r)
      osw[(lg * 4 + r) * 264 + nt * 16 + li] = (_Float16)(acc[nt][r] + bv);
  }
  _Float16* og = Xg + (size_t)tl * 65536 + (size_t)m0 * 1024 + nb * 256;
#pragma unroll
  for (int it = 0; it < 8; ++it) {
    int i = l + 64 * it;
    int row = i >> 5, c8 = i & 31;
    h8 v = *(const h8*)(const void*)&osw[row * 264 + c8 * 8];
    *(h8*)(void*)(og + (size_t)row * 1024 + c8 * 8) = v;
  }
}

// ---------------------------------------------------------------------------
// Phase 2: sequential LSTM, int8 (r17 math) + TWO BATCHES PER BLOCK:
// 32 blocks x 512 threads; each block advances batches b0=2*bid, b1=2*bid+1
// in the same iteration. Weights SHARED (no extra regs); two independent
// dependency streams per wave double the ILP the r17/r18 profile showed
// missing (2700 cyc/step with ~1000 cyc of pure latency stall); barrier
// count per step-pair halves. Demand ~117 <= 128 grant.
// Pool layout per buffer: batch0 [half0 128B |16B skew| half1 128B] at 0,
// batch1 at +288B -> all read groups hit disjoint bank quads.
// ---------------------------------------------------------------------------
#define CH8(M) M(0) M(1) M(2) M(3) M(4) M(5) M(6) M(7)
#define HB 144    // byte stride of one K-half within a batch's h buffer
#define BB 288    // byte stride between batch h buffers

__global__ __launch_bounds__(512, 1)
void klstm(const signed char* __restrict__ wq, const float* __restrict__ cs,
           const _Float16* __restrict__ Xg,
           const float* __restrict__ hsrc, const float* __restrict__ csrc,
           float* __restrict__ out,
           float* __restrict__ hN, float* __restrict__ cN,
           int t0, int Tc) {
  __shared__ __align__(16) char hp[2][2 * BB];   // [buf][batch*BB + pos]

  int tid = threadIdx.x;
  int b0 = blockIdx.x * 2;
  int b1 = b0 + 1;
  int p = tid & 1;
  int j = tid >> 1;

  const i4v* rF = (const i4v*)(wq + ((size_t)(0 * DH + j) * 256) + p * 128);
  const i4v* rI = (const i4v*)(wq + ((size_t)(1 * DH + j) * 256) + p * 128);
  const i4v* rG = (const i4v*)(wq + ((size_t)(2 * DH + j) * 256) + p * 128);
  const i4v* rO = (const i4v*)(wq + ((size_t)(3 * DH + j) * 256) + p * 128);

  // --- shared weights: 8 i4v chunks per gate row, named + pinned ---
#define DECLW(c) i4v QF_##c, QI_##c, QG_##c, QO_##c;
  CH8(DECLW)
#undef DECLW
#define LOADW(c) \
  QF_##c = rF[c]; QI_##c = rI[c]; QG_##c = rG[c]; QO_##c = rO[c];
  CH8(LOADW)
#undef LOADW
#define PINW(c) \
  asm volatile("" : "+v"(QF_##c)); asm volatile("" : "+v"(QI_##c)); \
  asm volatile("" : "+v"(QG_##c)); asm volatile("" : "+v"(QO_##c));
  CH8(PINW)
#undef PINW

  float cF = cs[0 * DH + j];
  float cI = cs[1 * DH + j];
  float cG = cs[2 * DH + j];
  float cO = cs[3 * DH + j];

  float creg0 = csrc[(size_t)b0 * DH + j];
  float creg1 = csrc[(size_t)b1 * DH + j];

  {
    // init h for both batches: tid covers 512 = 2 batches x 256 elements
    int bt = tid >> 8, e = tid & 255;
    int pos = (e < 128) ? e : (HB + e - 128);
    float hv = hsrc[(size_t)(b0 + bt) * DH + e];
    hp[0][bt * BB + pos] = (char)__float2int_rn(fminf(fmaxf(hv, -1.f), 1.f) * 127.f);
  }
  __syncthreads();

  const size_t xstep = (size_t)NB * G4;
  const _Float16* xA0p = Xg + (size_t)b0 * G4 + p * 512 + j;
  const _Float16* xB0p = xA0p + 256;
  const _Float16* xA1p = Xg + (size_t)b1 * G4 + p * 512 + j;
  const _Float16* xB1p = xA1p + 256;
  float xA0 = (float)xA0p[0], xB0 = (float)xB0p[0];
  float xA1 = (float)xA1p[0], xB1 = (float)xB1p[0];
  float hp0 = 0.f, hp1 = 0.f;       // pending out values
  float hl0 = 0.f, hl1 = 0.f;

  float* ob0 = out + (size_t)b0 * DH + j;
  float* ob1 = out + (size_t)b1 * DH + j;

  for (int t = 0; t < Tc; ++t) {
    if (p == 0 && t > 0) {
      ob0[(size_t)(t0 + t - 1) * NB * DH] = hp0;
      ob1[(size_t)(t0 + t - 1) * NB * DH] = hp1;
    }
    float xA0n = 0.f, xB0n = 0.f, xA1n = 0.f, xB1n = 0.f;
    if (t + 1 < Tc) {
      size_t o = (size_t)(t + 1) * xstep;
      xA0n = (float)xA0p[o]; xB0n = (float)xB0p[o];
      xA1n = (float)xA1p[o]; xB1n = (float)xB1p[o];
    }
    const char* hbA = hp[t & 1] + p * HB;          // batch0 K-half
    const char* hbB = hp[t & 1] + BB + p * HB;     // batch1 K-half

    int aF0 = 0, aI0 = 0, aG0 = 0, aO0 = 0;
    int aF1 = 0, aI1 = 0, aG1 = 0, aO1 = 0;
#define DOTC(c) { \
    i4v hA = *(const i4v*)(const void*)(hbA + 16 * (c)); \
    i4v hB = *(const i4v*)(const void*)(hbB + 16 * (c)); \
    aF0 = sdot4_(QF_##c[0], hA[0], aF0); aF1 = sdot4_(QF_##c[0], hB[0], aF1); \
    aF0 = sdot4_(QF_##c[1], hA[1], aF0); aF1 = sdot4_(QF_##c[1], hB[1], aF1); \
    aF0 = sdot4_(QF_##c[2], hA[2], aF0); aF1 = sdot4_(QF_##c[2], hB[2], aF1); \
    aF0 = sdot4_(QF_##c[3], hA[3], aF0); aF1 = sdot4_(QF_##c[3], hB[3], aF1); \
    aI0 = sdot4_(QI_##c[0], hA[0], aI0); aI1 = sdot4_(QI_##c[0], hB[0], aI1); \
    aI0 = sdot4_(QI_##c[1], hA[1], aI0); aI1 = sdot4_(QI_##c[1], hB[1], aI1); \
    aI0 = sdot4_(QI_##c[2], hA[2], aI0); aI1 = sdot4_(QI_##c[2], hB[2], aI1); \
    aI0 = sdot4_(QI_##c[3], hA[3], aI0); aI1 = sdot4_(QI_##c[3], hB[3], aI1); \
    aG0 = sdot4_(QG_##c[0], hA[0], aG0); aG1 = sdot4_(QG_##c[0], hB[0], aG1); \
    aG0 = sdot4_(QG_##c[1], hA[1], aG0); aG1 = sdot4_(QG_##c[1], hB[1], aG1); \
    aG0 = sdot4_(QG_##c[2], hA[2], aG0); aG1 = sdot4_(QG_##c[2], hB[2], aG1); \
    aG0 = sdot4_(QG_##c[3], hA[3], aG0); aG1 = sdot4_(QG_##c[3], hB[3], aG1); \
    aO0 = sdot4_(QO_##c[0], hA[0], aO0); aO1 = sdot4_(QO_##c[0], hB[0], aO1); \
    aO0 = sdot4_(QO_##c[1], hA[1], aO0); aO1 = sdot4_(QO_##c[1], hB[1], aO1); \
    aO0 = sdot4_(QO_##c[2], hA[2], aO0); aO1 = sdot4_(QO_##c[2], hB[2], aO1); \
    aO0 = sdot4_(QO_##c[3], hA[3], aO0); aO1 = sdot4_(QO_##c[3], hB[3], aO1); }
    CH8(DOTC)
#undef DOTC

    float vF0 = cF * (float)aF0 + (p ? 0.f : xA0);
    float vI0 = cI * (float)aI0 + (p ? 0.f : xB0);
    float vG0 = cG * (float)aG0 + (p ? xA0 : 0.f);
    float vO0 = cO * (float)aO0 + (p ? xB0 : 0.f);
    float vF1 = cF * (float)aF1 + (p ? 0.f : xA1);
    float vI1 = cI * (float)aI1 + (p ? 0.f : xB1);
    float vG1 = cG * (float)aG1 + (p ? xA1 : 0.f);
    float vO1 = cO * (float)aO1 + (p ? xB1 : 0.f);
    vF0 += dpp_swap1(vF0); vF1 += dpp_swap1(vF1);
    vI0 += dpp_swap1(vI0); vI1 += dpp_swap1(vI1);
    vG0 += dpp_swap1(vG0); vG1 += dpp_swap1(vG1);
    vO0 += dpp_swap1(vO0); vO1 += dpp_swap1(vO1);

    float f0 = sigmoid_(vF0), f1 = sigmoid_(vF1);
    float i0 = sigmoid_(vI0), i1 = sigmoid_(vI1);
    float g0 = tanh_(vG0),    g1 = tanh_(vG1);
    float o0 = sigmoid_(vO0), o1 = sigmoid_(vO1);

    creg0 = f0 * creg0 + i0 * g0;
    creg1 = f1 * creg1 + i1 * g1;
    float hn0 = o0 * tanh_(creg0);
    float hn1 = o1 * tanh_(creg1);
    hl0 = hn0; hl1 = hn1;
    hp0 = hn0; hp1 = hn1;
    if (p == 1) {
      int pos = (j < 128) ? j : (HB + j - 128);
      char* dst = hp[(t + 1) & 1];
      dst[pos]      = (char)__float2int_rn(hn0 * 127.f);
      dst[BB + pos] = (char)__float2int_rn(hn1 * 127.f);
    }
    __syncthreads();
    xA0 = xA0n; xB0 = xB0n; xA1 = xA1n; xB1 = xB1n;
  }

  if (p == 0) {
    ob0[(size_t)(t0 + Tc - 1) * NB * DH] = hp0;
    ob1[(size_t)(t0 + Tc - 1) * NB * DH] = hp1;
    hN[(size_t)b0 * DH + j] = hl0;
    hN[(size_t)b1 * DH + j] = hl1;
    cN[(size_t)b0 * DH + j] = creg0;
    cN[(size_t)b1 * DH + j] = creg1;
  }
}

// ---------------------------------------------------------------------------
extern "C" void kernel_launch(void* const* d_in, const int* in_sizes, int n_in,
                              void* d_out, int out_size, void* d_ws, size_t ws_size,
                              hipStream_t stream) {
  if (n_in < 11) return;
  const float* x  = (const float*)d_in[0];
  const float* h0 = (const float*)d_in[1];
  const float* c0 = (const float*)d_in[2];
  const float* Wf = (const float*)d_in[3];
  const float* bf = (const float*)d_in[4];
  const float* Wi = (const float*)d_in[5];
  const float* bi = (const float*)d_in[6];
  const float* Wg = (const float*)d_in[7];
  const float* bg = (const float*)d_in[8];
  const float* Wo = (const float*)d_in[9];
  const float* bo = (const float*)d_in[10];

  float* out = (float*)d_out;
  float* hN = out + (size_t)T_STEPS * NB * DH;
  float* cN = hN + (size_t)NB * DH;

  // ws layout: [Xg ring: Tc*128KB][wxfs 512KB][wq 256KB][cs 4KB]
  const size_t wxfBytes = (size_t)G4 * 128 * sizeof(h2);   // 512KB
  const size_t wqBytes  = (size_t)G4 * 256;                // 256KB
  const size_t csBytes  = (size_t)G4 * sizeof(float);      // 4KB
  const size_t fixedBytes = wxfBytes + wqBytes + csBytes;
  size_t avail = (ws_size > fixedBytes + 512) ? ws_size - fixedBytes - 512 : 0;
  const size_t perT = (size_t)NB * G4 * 2;  // 128KB per time step
  int Tc = (int)(avail / perT);
  if (Tc > T_STEPS) Tc = T_STEPS;
  if (Tc < 1) Tc = 1;

  _Float16* Xg = (_Float16*)d_ws;
  size_t xgBytes = ((size_t)Tc * perT + 255) / 256 * 256;
  h2* wxfs = (h2*)((char*)d_ws + xgBytes);
  signed char* wq = (signed char*)((char*)d_ws + xgBytes + wxfBytes);
  float* cs = (float*)((char*)d_ws + xgBytes + wxfBytes + wqBytes);

  kconv_w<<<dim3(512), dim3(256), 0, stream>>>(Wf, Wi, Wg, Wo, wxfs);
  kscale<<<dim3(4), dim3(256), 0, stream>>>(Wf, Wi, Wg, Wo, wq, cs);

  for (int t0 = 0; t0 < T_STEPS; t0 += Tc) {
    int tc = (T_STEPS - t0 < Tc) ? (T_STEPS - t0) : Tc;
    kxgemm<<<dim3(tc * 4), dim3(256), 0, stream>>>(x, (const h8*)wxfs,
                                                   bf, bi, bg, bo, Xg, t0);
    const float* hs = (t0 == 0) ? h0 : hN;
    const float* cs_ = (t0 == 0) ? c0 : cN;
    klstm<<<dim3(NB / 2), dim3(512), 0, stream>>>(wq, cs, Xg, hs, cs_,
                                                  out, hN, cN, t0, tc);
  }
}

// Round 20
// 1244.555 us; speedup vs baseline: 1.6235x; 1.6235x over previous
//
#include <hip/hip_runtime.h>
#include <cstdint>
#include <cstddef>

#define T_STEPS 1024
#define NB 64
#define DIN 256
#define DH 256
#define DW 512            // DIN + DH (row width of each W)
#define G4 1024           // 4*DH gate rows

typedef _Float16 h2 __attribute__((ext_vector_type(2)));
typedef _Float16 h4 __attribute__((ext_vector_type(4)));
typedef _Float16 h8 __attribute__((ext_vector_type(8)));
typedef float f4 __attribute__((ext_vector_type(4)));
typedef float f32x4 __attribute__((ext_vector_type(4)));
typedef int i4v __attribute__((ext_vector_type(4)));

static __device__ __forceinline__ float rcp_(float x) {
#if __has_builtin(__builtin_amdgcn_rcpf)
  return __builtin_amdgcn_rcpf(x);
#else
  return 1.0f / x;
#endif
}

static __device__ __forceinline__ float sigmoid_(float x) {
  return rcp_(1.f + __expf(-x));
}
static __device__ __forceinline__ float tanh_(float x) {
  float e = __expf(2.f * x);
  return 1.f - 2.f * rcp_(e + 1.f);
}

static __device__ __forceinline__ int sdot4_(int a, int b, int c) {
#if __has_builtin(__builtin_amdgcn_sdot4)
  return __builtin_amdgcn_sdot4(a, b, c, false);
#else
  int r = c;
#pragma unroll
  for (int k = 0; k < 4; ++k)
    r += (int)(signed char)(a >> (8 * k)) * (int)(signed char)(b >> (8 * k));
  return r;
#endif
}

// Pairwise lane swap (0<->1, ...) via DPP quad_perm [1,0,3,2] — pure VALU.
static __device__ __forceinline__ float dpp_swap1(float x) {
  int r = __builtin_amdgcn_update_dpp(0, __builtin_bit_cast(int, x),
                                      0xB1, 0xF, 0xF, true);
  return __builtin_bit_cast(float, r);
}

// ---------------------------------------------------------------------------
// x-part staging conversion (r15-exact): wxfs MFMA-staging order.
// ---------------------------------------------------------------------------
__global__ void kconv_w(const float* __restrict__ Wf, const float* __restrict__ Wi,
                        const float* __restrict__ Wg, const float* __restrict__ Wo,
                        h2* __restrict__ wxfs) {
  int kp = blockIdx.x >> 2;
  int gate = blockIdx.x & 3;
  int j = threadIdx.x;
  const float* W = gate == 0 ? Wf : gate == 1 ? Wi : gate == 2 ? Wg : Wo;
  const float* row = W + (size_t)j * DW;
  h2 v; v[0] = (_Float16)row[2*kp]; v[1] = (_Float16)row[2*kp + 1];
  int ks = kp >> 4, lg = (kp >> 2) & 3, slot = kp & 3;
  int nt = j >> 4, li = j & 15;
  size_t h8idx = (((size_t)gate * 8 + ks) * 16 + nt) * 64 + lg * 16 + li;
  wxfs[h8idx * 4 + slot] = v;
}

// ---------------------------------------------------------------------------
// h-part int8 quantization: per-row scale s = amax/127; cs = s/127.
// ---------------------------------------------------------------------------
__global__ void kscale(const float* __restrict__ Wf, const float* __restrict__ Wi,
                       const float* __restrict__ Wg, const float* __restrict__ Wo,
                       signed char* __restrict__ wq, float* __restrict__ cs) {
  int gate = blockIdx.x;
  int j = threadIdx.x;
  const float* W = gate == 0 ? Wf : gate == 1 ? Wi : gate == 2 ? Wg : Wo;
  const float* row = W + (size_t)j * DW + DIN;
  float amax = 1e-8f;
#pragma unroll 4
  for (int k4 = 0; k4 < 64; ++k4) {
    f4 v = *(const f4*)(row + 4 * k4);
    amax = fmaxf(amax, fmaxf(fmaxf(fabsf(v[0]), fabsf(v[1])),
                             fmaxf(fabsf(v[2]), fabsf(v[3]))));
  }
  int gr = gate * 256 + j;
  cs[gr] = amax / (127.f * 127.f);
  float inv = 127.f / amax;
  signed char* dst = wq + (size_t)gr * 256;
#pragma unroll 4
  for (int k4 = 0; k4 < 64; ++k4) {
    f4 v = *(const f4*)(row + 4 * k4);
#pragma unroll
    for (int u = 0; u < 4; ++u)
      dst[4 * k4 + u] = (signed char)__float2int_rn(v[u] * inv);
  }
}

// ---------------------------------------------------------------------------
// Phase 1 (MFMA v3, r15-exact — ~62us measured): Xg = x.Wx^T + bias.
// ---------------------------------------------------------------------------
__launch_bounds__(256, 2)
__global__ void kxgemm(const float* __restrict__ x,
                       const h8* __restrict__ wxfs,
                       const float* __restrict__ bf, const float* __restrict__ bi,
                       const float* __restrict__ bg, const float* __restrict__ bo,
                       _Float16* __restrict__ Xg,
                       int t0) {
  __shared__ char pool[65536];
  h8 (*xsf)[8][64] = (h8(*)[8][64])pool;               // 32KB A-frags
  h8 (*bs)[1024] = (h8(*)[1024])(pool + 32768);        // 2x16KB B slabs

  int tid = threadIdx.x;
  int l = tid & 63;
  int w = tid >> 6;
  int li = l & 15, lg = l >> 4;
  int tl = blockIdx.x >> 2;
  int nb = blockIdx.x & 3;
  int m0 = w * 16;

#pragma unroll
  for (int i = 0; i < 8; ++i) {
    int hi = tid + 256 * i;
    int sw  = hi >> 9;
    int sks = (hi >> 6) & 7;
    int sl  = hi & 63;
    int sli = sl & 15, slg = sl >> 4;
    const float* src = x + ((size_t)(t0 + tl) * NB + sw * 16 + sli) * DIN
                     + sks * 32 + slg * 8;
    f4 a0 = *(const f4*)src;
    f4 a1 = *(const f4*)(src + 4);
    h8 a;
    a[0] = (_Float16)a0[0]; a[1] = (_Float16)a0[1];
    a[2] = (_Float16)a0[2]; a[3] = (_Float16)a0[3];
    a[4] = (_Float16)a1[0]; a[5] = (_Float16)a1[1];
    a[6] = (_Float16)a1[2]; a[7] = (_Float16)a1[3];
    xsf[sw][sks][sl] = a;
  }
  {
    const h8* wsrc = wxfs + (size_t)(nb * 8 + 0) * 1024;
#pragma unroll
    for (int i = 0; i < 4; ++i) bs[0][tid + 256 * i] = wsrc[tid + 256 * i];
  }
  __syncthreads();

  f32x4 acc[16];
#pragma unroll
  for (int nt = 0; nt < 16; ++nt) {
    acc[nt][0] = 0.f; acc[nt][1] = 0.f; acc[nt][2] = 0.f; acc[nt][3] = 0.f;
  }

  for (int ks = 0; ks < 8; ++ks) {
    int buf = ks & 1;
    h8 ld0, ld1, ld2, ld3;
    if (ks < 7) {
      const h8* wn = wxfs + (size_t)(nb * 8 + ks + 1) * 1024;
      ld0 = wn[tid]; ld1 = wn[tid + 256]; ld2 = wn[tid + 512]; ld3 = wn[tid + 768];
    }
    h8 a = xsf[w][ks][l];
#pragma unroll
    for (int nt = 0; nt < 16; ++nt) {
      h8 bb = bs[buf][nt * 64 + l];
      acc[nt] = __builtin_amdgcn_mfma_f32_16x16x32_f16(a, bb, acc[nt], 0, 0, 0);
    }
    if (ks < 7) {
      h8* bt = bs[buf ^ 1];
      bt[tid] = ld0; bt[tid + 256] = ld1; bt[tid + 512] = ld2; bt[tid + 768] = ld3;
    }
    __syncthreads();
  }

  _Float16* osw = (_Float16*)(pool + (size_t)w * 8448);   // [16][264]
  const float* biasp = nb == 0 ? bf : nb == 1 ? bi : nb == 2 ? bg : bo;
#pragma unroll
  for (int nt = 0; nt < 16; ++nt) {
    float bv = biasp[nt * 16 + li];
#pragma unroll
    for (int r = 0; r < 4; ++r)
      osw[(lg * 4 + r) * 264 + nt * 16 + li] = (_Float16)(acc[nt][r] + bv);
  }
  _Float16* og = Xg + (size_t)tl * 65536 + (size_t)m0 * 1024 + nb * 256;
#pragma unroll
  for (int it = 0; it < 8; ++it) {
    int i = l + 64 * it;
    int row = i >> 5, c8 = i & 31;
    h8 v = *(const h8*)(const void*)&osw[row * 264 + c8 * 8];
    *(h8*)(void*)(og + (size_t)row * 1024 + c8 * 8) = v;
  }
}

// ---------------------------------------------------------------------------
// Phase 2 (r17-exact, best measured 1144us): sequential LSTM, int8 weights+h.
// 512 threads; thread (j = tid>>1, p = tid&1) owns all 4 gate rows of unit j
// over its K-half as 4x8 named i4v (128 VGPRs) — weight set register-resident.
// 8 b128 h-broadcast LDS reads/step; halves skewed 16B -> disjoint banks.
// preact_h = cs[row] * sdot4-accum; x seeded p-conditionally + DPP combine.
// 86KB referenced LDS pool pins occupancy so the 128-VGPR grant holds.
// ---------------------------------------------------------------------------
#define CH8(M) M(0) M(1) M(2) M(3) M(4) M(5) M(6) M(7)
#define HB 144   // byte stride of one K-half in h buffer (128 + 16 skew)

__global__ __launch_bounds__(512, 1)
void klstm(const signed char* __restrict__ wq, const float* __restrict__ cs,
           const _Float16* __restrict__ Xg,
           const float* __restrict__ hsrc, const float* __restrict__ csrc,
           float* __restrict__ out,
           float* __restrict__ hN, float* __restrict__ cN,
           int t0, int Tc) {
  __shared__ __align__(16) char hpool[2][43008];   // 84KB pool; h at head

  int tid = threadIdx.x;
  int b = blockIdx.x;
  int p = tid & 1;
  int j = tid >> 1;

  const i4v* rF = (const i4v*)(wq + ((size_t)(0 * DH + j) * 256) + p * 128);
  const i4v* rI = (const i4v*)(wq + ((size_t)(1 * DH + j) * 256) + p * 128);
  const i4v* rG = (const i4v*)(wq + ((size_t)(2 * DH + j) * 256) + p * 128);
  const i4v* rO = (const i4v*)(wq + ((size_t)(3 * DH + j) * 256) + p * 128);

  // --- weights: 8 i4v chunks per gate row, named + pinned ---
#define DECLW(c) i4v QF_##c, QI_##c, QG_##c, QO_##c;
  CH8(DECLW)
#undef DECLW
#define LOADW(c) \
  QF_##c = rF[c]; QI_##c = rI[c]; QG_##c = rG[c]; QO_##c = rO[c];
  CH8(LOADW)
#undef LOADW
#define PINW(c) \
  asm volatile("" : "+v"(QF_##c)); asm volatile("" : "+v"(QI_##c)); \
  asm volatile("" : "+v"(QG_##c)); asm volatile("" : "+v"(QO_##c));
  CH8(PINW)
#undef PINW

  float cF = cs[0 * DH + j];
  float cI = cs[1 * DH + j];
  float cG = cs[2 * DH + j];
  float cO = cs[3 * DH + j];

  float creg = csrc[(size_t)b * DH + j];
  if (tid < 256) {
    int pos = (tid < 128) ? tid : (HB + tid - 128);
    float hv = hsrc[(size_t)b * DH + tid];
    hpool[0][pos] = (char)__float2int_rn(fminf(fmaxf(hv, -1.f), 1.f) * 127.f);
  }
  __syncthreads();

  const size_t xstep = (size_t)NB * G4;
  const _Float16* xpA = Xg + (size_t)b * G4 + p * 512 + j;   // f or g
  const _Float16* xpB = xpA + 256;                           // i or o
  float xA = (float)xpA[0], xB = (float)xpB[0];
  float hlast = 0.f;

  for (int t = 0; t < Tc; ++t) {
    float xAn = 0.f, xBn = 0.f;
    if (t + 1 < Tc) {
      xAn = (float)xpA[(size_t)(t + 1) * xstep];
      xBn = (float)xpB[(size_t)(t + 1) * xstep];
    }
    const char* hb = hpool[t & 1] + p * HB;

    int aF = 0, aI = 0, aG = 0, aO = 0;
#define DOTC(c) { \
    i4v hv = *(const i4v*)(const void*)(hb + 16 * (c)); \
    aF = sdot4_(QF_##c[0], hv[0], aF); aF = sdot4_(QF_##c[1], hv[1], aF); \
    aF = sdot4_(QF_##c[2], hv[2], aF); aF = sdot4_(QF_##c[3], hv[3], aF); \
    aI = sdot4_(QI_##c[0], hv[0], aI); aI = sdot4_(QI_##c[1], hv[1], aI); \
    aI = sdot4_(QI_##c[2], hv[2], aI); aI = sdot4_(QI_##c[3], hv[3], aI); \
    aG = sdot4_(QG_##c[0], hv[0], aG); aG = sdot4_(QG_##c[1], hv[1], aG); \
    aG = sdot4_(QG_##c[2], hv[2], aG); aG = sdot4_(QG_##c[3], hv[3], aG); \
    aO = sdot4_(QO_##c[0], hv[0], aO); aO = sdot4_(QO_##c[1], hv[1], aO); \
    aO = sdot4_(QO_##c[2], hv[2], aO); aO = sdot4_(QO_##c[3], hv[3], aO); }
    CH8(DOTC)
#undef DOTC

    // scale to float + seed x once (p-conditional) + pair-combine via DPP
    float vF = cF * (float)aF + (p ? 0.f : xA);
    float vI = cI * (float)aI + (p ? 0.f : xB);
    float vG = cG * (float)aG + (p ? xA : 0.f);
    float vO = cO * (float)aO + (p ? xB : 0.f);
    vF += dpp_swap1(vF);
    vI += dpp_swap1(vI);
    vG += dpp_swap1(vG);
    vO += dpp_swap1(vO);

    float f_ = sigmoid_(vF);
    float i_ = sigmoid_(vI);
    float g_ = tanh_(vG);
    float o_ = sigmoid_(vO);

    creg = f_ * creg + i_ * g_;
    float hn = o_ * tanh_(creg);
    hlast = hn;
    if (p == 0) {
      out[((size_t)(t0 + t) * NB + b) * DH + j] = hn;
    } else {
      int pos = (j < 128) ? j : (HB + j - 128);
      hpool[(t + 1) & 1][pos] = (char)__float2int_rn(hn * 127.f);
    }
    __syncthreads();
    xA = xAn; xB = xBn;
  }

  if (p == 0) {
    hN[(size_t)b * DH + j] = hlast;
    cN[(size_t)b * DH + j] = creg;
  }
}

// ---------------------------------------------------------------------------
extern "C" void kernel_launch(void* const* d_in, const int* in_sizes, int n_in,
                              void* d_out, int out_size, void* d_ws, size_t ws_size,
                              hipStream_t stream) {
  if (n_in < 11) return;
  const float* x  = (const float*)d_in[0];
  const float* h0 = (const float*)d_in[1];
  const float* c0 = (const float*)d_in[2];
  const float* Wf = (const float*)d_in[3];
  const float* bf = (const float*)d_in[4];
  const float* Wi = (const float*)d_in[5];
  const float* bi = (const float*)d_in[6];
  const float* Wg = (const float*)d_in[7];
  const float* bg = (const float*)d_in[8];
  const float* Wo = (const float*)d_in[9];
  const float* bo = (const float*)d_in[10];

  float* out = (float*)d_out;
  float* hN = out + (size_t)T_STEPS * NB * DH;
  float* cN = hN + (size_t)NB * DH;

  // ws layout: [Xg ring: Tc*128KB][wxfs 512KB][wq 256KB][cs 4KB]
  const size_t wxfBytes = (size_t)G4 * 128 * sizeof(h2);   // 512KB
  const size_t wqBytes  = (size_t)G4 * 256;                // 256KB
  const size_t csBytes  = (size_t)G4 * sizeof(float);      // 4KB
  const size_t fixedBytes = wxfBytes + wqBytes + csBytes;
  size_t avail = (ws_size > fixedBytes + 512) ? ws_size - fixedBytes - 512 : 0;
  const size_t perT = (size_t)NB * G4 * 2;  // 128KB per time step
  int Tc = (int)(avail / perT);
  if (Tc > T_STEPS) Tc = T_STEPS;
  if (Tc < 1) Tc = 1;

  _Float16* Xg = (_Float16*)d_ws;
  size_t xgBytes = ((size_t)Tc * perT + 255) / 256 * 256;
  h2* wxfs = (h2*)((char*)d_ws + xgBytes);
  signed char* wq = (signed char*)((char*)d_ws + xgBytes + wxfBytes);
  float* cs = (float*)((char*)d_ws + xgBytes + wxfBytes + wqBytes);

  kconv_w<<<dim3(512), dim3(256), 0, stream>>>(Wf, Wi, Wg, Wo, wxfs);
  kscale<<<dim3(4), dim3(256), 0, stream>>>(Wf, Wi, Wg, Wo, wq, cs);

  for (int t0 = 0; t0 < T_STEPS; t0 += Tc) {
    int tc = (T_STEPS - t0 < Tc) ? (T_STEPS - t0) : Tc;
    kxgemm<<<dim3(tc * 4), dim3(256), 0, stream>>>(x, (const h8*)wxfs,
                                                   bf, bi, bg, bo, Xg, t0);
    const float* hs = (t0 == 0) ? h0 : hN;
    const float* cs_ = (t0 == 0) ? c0 : cN;
    klstm<<<dim3(NB), dim3(512), 0, stream>>>(wq, cs, Xg, hs, cs_,
                                              out, hN, cN, t0, tc);
  }
}